// Round 10
// baseline (28.049 us; speedup 1.0000x reference)
//
#include <hip/hip_runtime.h>
#include <math.h>

#define NN 1024
#define BTH 512
#define NT 16              // NN/64 tile-chunks per row
#define NTILES 136         // NT*(NT+1)/2 upper-triangle 64x64 tiles
#define TBLK 17            // tile blocks per batch (8 waves = 8 tiles each)
#define BPB (TBLK + 1)     // blocks per batch incl. its top-k block = 18

// ws byte offsets. All data slots are OVERWRITTEN (atomicExch) every launch
// before any read -> no reset needed, immune to initial garbage/poison.
//   slotT[32][136] f32 @ 0       per-tile partial sums
//   slotC[32]      f32 @ 17408   per-batch top-k correction
//   slotV[32]      f32 @ 17536   per-batch valid-pair count
//   lossS[32]      f32 @ 17664   per-batch loss
//   ctrB[b]        u32 @ 17792 + b*128   (own cache line each)
//   ctrG           u32 @ 21888
// Tickets: atomicInc wraparound (LIMIT = P-1). Counter cycles 0..P-1; ANY
// start >= P-1 (0xAA poison or steady-state residue P-1) wraps to 0 at the
// first arrival, so old == P-2 identifies exactly the LAST arrival, every
// launch, with no reset dispatch. (Round-9-validated protocol.)
#define OFF_T 0
#define OFF_C 17408
#define OFF_V 17536
#define OFF_L 17664
#define OFF_CB 17792
#define OFF_CG 21888

// f(i,j) = softplus(x) - t*x  (t = [ri>rj]), gated by valid = [ri!=rj].
// Identity: sp(x) - t*x = sp((1-2t)x)  =>  symmetric: f(i,j) = f(j,i).
__device__ __forceinline__ float pair_f(float pi, float ri, float pj, float rj) {
    const float x = pi - pj;
    const float y = (ri > rj) ? -x : x;
    const float e = __expf(-fabsf(y));
    const float f = fmaxf(y, 0.0f) + __logf(1.0f + e);
    return (ri != rj) ? f : 0.0f;
}

// Keep a returning atomic's result live -> ordered before later vmem ops.
__device__ __forceinline__ void sinkf(float v) { asm volatile("" :: "v"(v)); }

// Lexicographic order (value desc, index asc) = jax.lax.top_k tie-break.
// Total order over distinct (v,i) -> merge-order-independent top-3.
__device__ __forceinline__ bool better(float v, int i, float V, int I) {
    return (v > V) || (v == V && i < I);
}
__device__ __forceinline__ void ins3(float x, int ix,
                                     float& a1, int& i1, float& a2, int& i2,
                                     float& a3, int& i3) {
    if (better(x, ix, a1, i1))      { a3=a2; i3=i2; a2=a1; i2=i1; a1=x; i1=ix; }
    else if (better(x, ix, a2, i2)) { a3=a2; i3=i2; a2=x;  i2=ix; }
    else if (better(x, ix, a3, i3)) { a3=x;  i3=ix; }
}

// ---------------------------------------------------------------------------
// ONE dispatch. Cross-block data via device-scope atomics only (coherent
// across XCDs, no fences); per-batch counters on private 128-B lines.
// 512-thread blocks: 18 ticket arrivals/batch (was 35) -> halved same-line
// atomicInc serialization before the winner (last) arrival.
//   blocks [0,B):        per-batch one-pass top-3 + correction + valid count
//   blocks [B, B+17*B):  8 waves x one 64x64 upper-triangle tile each
// ---------------------------------------------------------------------------
__global__ void __launch_bounds__(BTH)
fused_kernel(const float* __restrict__ pred, const float* __restrict__ rel,
             char* __restrict__ ws, float* __restrict__ out, int B) {
    const int t = threadIdx.x;
    const int w = t >> 6, l = t & 63;
    const int blk = blockIdx.x;

    __shared__ float  s_p[NN];
    __shared__ float  s_r[NN];
    __shared__ float2 s_seg[8][64];
    __shared__ float  s_tv[8][3];
    __shared__ int    s_ti[8][3];
    __shared__ int    s_hist[8][5];
    __shared__ float  s_red[8];
    __shared__ float  s_corr, s_cnt;
    __shared__ int    s_flag, s_flag2;

    float* slotT = (float*)(ws + OFF_T);
    float* slotC = (float*)(ws + OFF_C);
    float* slotV = (float*)(ws + OFF_V);
    float* lossS = (float*)(ws + OFF_L);

    int b;
    if (blk < B) {
        // ---------------- top-k path: one block per batch ----------------
        b = blk;
        const size_t base = (size_t)b * NN;
        const float2 p2 = ((const float2*)(pred + base))[t];
        const float2 r2 = ((const float2*)(rel  + base))[t];
        ((float2*)s_p)[t] = p2;
        ((float2*)s_r)[t] = r2;

        // grade histogram via ballots
        for (int g = 0; g < 5; ++g) {
            const float gf = (float)g;
            const int c = __popcll(__ballot(r2.x == gf)) + __popcll(__ballot(r2.y == gf));
            if (l == 0) s_hist[w][g] = c;
        }

        // per-thread sorted top-3 (from its 2 elements)
        const int n0 = t * 2;
        float a1, a2, a3; int i1, i2, i3;
        if (p2.y > p2.x) { a1 = p2.y; i1 = n0 + 1; a2 = p2.x; i2 = n0; }
        else             { a1 = p2.x; i1 = n0;     a2 = p2.y; i2 = n0 + 1; }
        a3 = -INFINITY; i3 = NN;

        // one-pass butterfly merge across the wave (read b's BEFORE inserts)
        for (int off = 32; off > 0; off >>= 1) {
            const float b1 = __shfl_xor(a1, off), b2 = __shfl_xor(a2, off),
                        b3 = __shfl_xor(a3, off);
            const int   j1 = __shfl_xor(i1, off), j2 = __shfl_xor(i2, off),
                        j3 = __shfl_xor(i3, off);
            ins3(b1, j1, a1, i1, a2, i2, a3, i3);
            ins3(b2, j2, a1, i1, a2, i2, a3, i3);
            ins3(b3, j3, a1, i1, a2, i2, a3, i3);
        }
        if (l == 0) {
            s_tv[w][0] = a1; s_tv[w][1] = a2; s_tv[w][2] = a3;
            s_ti[w][0] = i1; s_ti[w][1] = i2; s_ti[w][2] = i3;
        }
        __syncthreads();   // also publishes s_p / s_r for rowsums below

        // merge the 8 wave triples -> identical global top-3 in every thread
        float c1 = s_tv[0][0], c2 = s_tv[0][1], c3 = s_tv[0][2];
        int   d1 = s_ti[0][0], d2 = s_ti[0][1], d3 = s_ti[0][2];
        for (int q = 1; q < 8; ++q) {
            ins3(s_tv[q][0], s_ti[q][0], c1, d1, c2, d2, c3, d3);
            ins3(s_tv[q][1], s_ti[q][1], c1, d1, c2, d2, c3, d3);
            ins3(s_tv[q][2], s_ti[q][2], c1, d1, c2, d2, c3, d3);
        }
        const int w1 = d1, w2 = d2, w3 = d3;

        // unweighted rowsums over the 3 winners (2 cols per thread)
        float part = 0.0f;
        for (int k = 0; k < 3; ++k) {
            const int row = (k == 0) ? w1 : (k == 1) ? w2 : w3;
            const float pk = s_p[row], rk = s_r[row];
            part += pair_f(pk, rk, s_p[t],       s_r[t]);
            part += pair_f(pk, rk, s_p[t + BTH], s_r[t + BTH]);
        }
        for (int off = 32; off > 0; off >>= 1) part += __shfl_down(part, off);
        if (l == 0) s_red[w] = part;
        __syncthreads();
        if (t == 0) {
            float R = 0.0f;
            for (int q = 0; q < 8; ++q) R += s_red[q];
            const float TT = 2.0f * (pair_f(s_p[w1], s_r[w1], s_p[w2], s_r[w2])
                                   + pair_f(s_p[w1], s_r[w1], s_p[w3], s_r[w3])
                                   + pair_f(s_p[w2], s_r[w2], s_p[w3], s_r[w3]));
            // W = 1 + m_i + m_j + m_i*m_j  =>  weighted = S + 2R + TT
            atomicExch(&slotC[b], 2.0f * R + TT);                 // overwrite
            int s2 = 0;
            for (int g = 0; g < 5; ++g) {
                int cg = 0;
                for (int q = 0; q < 8; ++q) cg += s_hist[q][g];
                s2 += cg * cg;
            }
            atomicExch(&slotV[b], (float)(NN * NN - s2));         // overwrite
        }
    } else {
        // ---------------- tile path: one wave per 64x64 tile (8/block) ----------------
        const int idx = blk - B;
        b = idx / TBLK;
        const int L = (idx % TBLK) * 8 + w;     // 0..135
        int rem = L, ti = 0;
        while (rem >= NT - ti) { rem -= NT - ti; ++ti; }
        const int tj = ti + rem;
        const size_t base = (size_t)b * NN;
        const int i0 = ti * 64, j0 = tj * 64;

        const float jp = pred[base + j0 + l];
        const float jr = rel [base + j0 + l];
        // per-wave private LDS segment (wave-lockstep + lgkmcnt, no barrier)
        s_seg[w][l] = make_float2(pred[base + i0 + l], rel[base + i0 + l]);

        float a = 0.0f;
        if (ti != tj) {
#pragma unroll 16
            for (int ii = 0; ii < 64; ++ii) {
                const float2 v = s_seg[w][ii];
                a += pair_f(v.x, v.y, jp, jr);
            }
        } else {
#pragma unroll 16
            for (int ii = 0; ii < 64; ++ii) {
                const float2 v = s_seg[w][ii];
                const float f = pair_f(v.x, v.y, jp, jr);
                a += (l > ii) ? f : 0.0f;       // strict upper triangle
            }
        }
        for (int off = 32; off > 0; off >>= 1) a += __shfl_down(a, off);
        if (l == 0)
            atomicExch(&slotT[(size_t)b * NTILES + L], 2.0f * a); // overwrite
    }

    // __syncthreads drains vmcnt: this block's slot writes are performed at
    // the coherence point before its ticket is taken.
    __syncthreads();
    if (t == 0) {
        unsigned int* ctr_b = (unsigned int*)(ws + OFF_CB + (size_t)b * 128);
        const unsigned int old = atomicInc(ctr_b, (unsigned int)(BPB - 1));
        s_flag = (old == (unsigned int)(BPB - 2)) ? 1 : 0;
    }
    __syncthreads();
    if (!s_flag) return;                         // block-uniform

    // ------------- batch winner: all 18 blocks of batch b are done -------------
    {
        float v = 0.0f;
        if (t < NTILES)            v = atomicAdd(&slotT[(size_t)b * NTILES + t], 0.0f);
        else if (t == NTILES)      s_corr = atomicAdd(&slotC[b], 0.0f);
        else if (t == NTILES + 1)  s_cnt  = atomicAdd(&slotV[b], 0.0f);
        for (int off = 32; off > 0; off >>= 1) v += __shfl_down(v, off);
        if (l == 0) s_red[w] = v;
        __syncthreads();
        if (t == 0) {
            float S = 0.0f;
            for (int q = 0; q < 8; ++q) S += s_red[q];
            const float loss_b = (S + s_corr) / (s_cnt + 1e-8f);
            sinkf(atomicExch(&lossS[b], loss_b));        // ordered before ticket
            unsigned int* ctrG = (unsigned int*)(ws + OFF_CG);
            const unsigned int o2 = atomicInc(ctrG, (unsigned int)(B - 1));
            s_flag2 = (o2 == (unsigned int)(B - 2)) ? 1 : 0;
        }
        __syncthreads();
        if (s_flag2 && w == 0) {
            // ------------- global winner: all 32 batch losses written -------------
            float u = (l < B) ? atomicAdd(&lossS[l], 0.0f) : 0.0f;
            for (int off = 32; off > 0; off >>= 1) u += __shfl_down(u, off);
            if (l == 0) out[0] = u / (float)B;
        }
    }
}

extern "C" void kernel_launch(void* const* d_in, const int* in_sizes, int n_in,
                              void* d_out, int out_size, void* d_ws, size_t ws_size,
                              hipStream_t stream) {
    const float* pred = (const float*)d_in[0];
    const float* rel  = (const float*)d_in[1];
    float* out = (float*)d_out;

    const int B = in_sizes[0] / NN;  // 32

    fused_kernel<<<B + TBLK * B, BTH, 0, stream>>>(pred, rel, (char*)d_ws, out, B);
}

// Round 11
// 25.793 us; speedup vs baseline: 1.0875x; 1.0875x over previous
//
#include <hip/hip_runtime.h>
#include <math.h>

#define NN 1024
#define BTH 256
#define NT 16              // NN/64 tile-chunks per row
#define NTILES 136         // NT*(NT+1)/2 upper-triangle 64x64 tiles
#define TBLK 34            // tile blocks per batch (4 waves = 4 tiles each)
#define BPB (TBLK + 1)     // blocks per batch incl. its top-k block = 35

// ws byte offsets. All data slots are OVERWRITTEN (atomicExch) every launch
// before any read -> no reset needed, immune to initial garbage/poison.
//   slotT[32][136] f32 @ 0       per-tile partial sums
//   slotC[32]      f32 @ 17408   per-batch top-k correction
//   slotV[32]      f32 @ 17536   per-batch valid-pair count
//   lossS[32]      f32 @ 17664   per-batch loss
//   ctrB[b]        u32 @ 17792 + b*128   (own cache line each)
//   ctrG           u32 @ 21888
// Tickets: atomicInc wraparound (LIMIT = P-1). Counter cycles 0..P-1; ANY
// start >= P-1 (0xAA poison or steady-state residue P-1) wraps to 0 at the
// first arrival, so old == P-2 identifies exactly the LAST arrival, every
// launch, with no reset dispatch. (Round-9-validated protocol.)
#define OFF_T 0
#define OFF_C 17408
#define OFF_V 17536
#define OFF_L 17664
#define OFF_CB 17792
#define OFF_CG 21888

// f(i,j) = softplus(x) - t*x  (t = [ri>rj]), gated by valid = [ri!=rj].
// Identity: sp(x) - t*x = sp((1-2t)x)  =>  symmetric: f(i,j) = f(j,i).
__device__ __forceinline__ float pair_f(float pi, float ri, float pj, float rj) {
    const float x = pi - pj;
    const float y = (ri > rj) ? -x : x;
    const float e = __expf(-fabsf(y));
    const float f = fmaxf(y, 0.0f) + __logf(1.0f + e);
    return (ri != rj) ? f : 0.0f;
}

// Keep a returning atomic's result live -> ordered before later vmem ops.
__device__ __forceinline__ void sinkf(float v) { asm volatile("" :: "v"(v)); }

// Lexicographic order (value desc, index asc) = jax.lax.top_k tie-break.
// Total order over distinct (v,i) -> merge-order-independent top-3.
__device__ __forceinline__ bool better(float v, int i, float V, int I) {
    return (v > V) || (v == V && i < I);
}
__device__ __forceinline__ void ins3(float x, int ix,
                                     float& a1, int& i1, float& a2, int& i2,
                                     float& a3, int& i3) {
    if (better(x, ix, a1, i1))      { a3=a2; i3=i2; a2=a1; i2=i1; a1=x; i1=ix; }
    else if (better(x, ix, a2, i2)) { a3=a2; i3=i2; a2=x;  i2=ix; }
    else if (better(x, ix, a3, i3)) { a3=x;  i3=ix; }
}

// ---------------------------------------------------------------------------
// ONE dispatch (round-9 winner structure: 256-thread blocks, 4 waves).
// Cross-block data via device-scope atomics only (coherent across XCDs, no
// fences); per-batch counters on private 128-B lines. Only delta vs round 9:
// one-pass top-3 (register sort + butterfly merge) -> ~2 barriers instead of
// ~7 in the grid's longest block.
//   blocks [0,B):        per-batch top-3 + correction + valid count
//   blocks [B, B+34*B):  4 waves x one 64x64 upper-triangle tile each
// ---------------------------------------------------------------------------
__global__ void __launch_bounds__(BTH)
fused_kernel(const float* __restrict__ pred, const float* __restrict__ rel,
             char* __restrict__ ws, float* __restrict__ out, int B) {
    const int t = threadIdx.x;
    const int w = t >> 6, l = t & 63;
    const int blk = blockIdx.x;

    __shared__ float  s_p[NN];
    __shared__ float  s_r[NN];
    __shared__ float2 s_seg[4][64];
    __shared__ float  s_tv[4][3];
    __shared__ int    s_ti[4][3];
    __shared__ int    s_hist[4][5];
    __shared__ float  s_red[4];
    __shared__ float  s_corr, s_cnt;
    __shared__ int    s_flag, s_flag2;

    float* slotT = (float*)(ws + OFF_T);
    float* slotC = (float*)(ws + OFF_C);
    float* slotV = (float*)(ws + OFF_V);
    float* lossS = (float*)(ws + OFF_L);

    int b;
    if (blk < B) {
        // ---------------- top-k path: one block per batch ----------------
        b = blk;
        const size_t base = (size_t)b * NN;
        const float4 p4 = ((const float4*)(pred + base))[t];
        const float4 r4 = ((const float4*)(rel  + base))[t];
        ((float4*)s_p)[t] = p4;
        ((float4*)s_r)[t] = r4;

        // grade histogram via ballots (no LDS atomics)
        for (int g = 0; g < 5; ++g) {
            const float gf = (float)g;
            const int c = __popcll(__ballot(r4.x == gf)) + __popcll(__ballot(r4.y == gf))
                        + __popcll(__ballot(r4.z == gf)) + __popcll(__ballot(r4.w == gf));
            if (l == 0) s_hist[w][g] = c;
        }

        // per-thread sorted top-3 of its 4 elements (ascending index inserts)
        const int n0 = t * 4;
        float a1 = -INFINITY, a2 = -INFINITY, a3 = -INFINITY;
        int   i1 = NN, i2 = NN, i3 = NN;
        ins3(p4.x, n0 + 0, a1, i1, a2, i2, a3, i3);
        ins3(p4.y, n0 + 1, a1, i1, a2, i2, a3, i3);
        ins3(p4.z, n0 + 2, a1, i1, a2, i2, a3, i3);
        ins3(p4.w, n0 + 3, a1, i1, a2, i2, a3, i3);

        // one-pass butterfly merge across the wave (read partners BEFORE inserts)
        for (int off = 32; off > 0; off >>= 1) {
            const float b1 = __shfl_xor(a1, off), b2 = __shfl_xor(a2, off),
                        b3 = __shfl_xor(a3, off);
            const int   j1 = __shfl_xor(i1, off), j2 = __shfl_xor(i2, off),
                        j3 = __shfl_xor(i3, off);
            ins3(b1, j1, a1, i1, a2, i2, a3, i3);
            ins3(b2, j2, a1, i1, a2, i2, a3, i3);
            ins3(b3, j3, a1, i1, a2, i2, a3, i3);
        }
        if (l == 0) {
            s_tv[w][0] = a1; s_tv[w][1] = a2; s_tv[w][2] = a3;
            s_ti[w][0] = i1; s_ti[w][1] = i2; s_ti[w][2] = i3;
        }
        __syncthreads();   // publishes wave triples AND s_p/s_r

        // merge the 4 wave triples -> identical global top-3 in every thread
        float c1 = s_tv[0][0], c2 = s_tv[0][1], c3 = s_tv[0][2];
        int   d1 = s_ti[0][0], d2 = s_ti[0][1], d3 = s_ti[0][2];
        for (int q = 1; q < 4; ++q) {
            ins3(s_tv[q][0], s_ti[q][0], c1, d1, c2, d2, c3, d3);
            ins3(s_tv[q][1], s_ti[q][1], c1, d1, c2, d2, c3, d3);
            ins3(s_tv[q][2], s_ti[q][2], c1, d1, c2, d2, c3, d3);
        }
        const int w1 = d1, w2 = d2, w3 = d3;

        // unweighted rowsums over the 3 winners (4 cols per thread)
        float part = 0.0f;
        for (int k = 0; k < 3; ++k) {
            const int row = (k == 0) ? w1 : (k == 1) ? w2 : w3;
            const float pk = s_p[row], rk = s_r[row];
#pragma unroll
            for (int c = 0; c < 4; ++c) {
                const int j = t + c * BTH;
                part += pair_f(pk, rk, s_p[j], s_r[j]);
            }
        }
        for (int off = 32; off > 0; off >>= 1) part += __shfl_down(part, off);
        if (l == 0) s_red[w] = part;
        __syncthreads();
        if (t == 0) {
            const float R = s_red[0] + s_red[1] + s_red[2] + s_red[3];
            const float TT = 2.0f * (pair_f(s_p[w1], s_r[w1], s_p[w2], s_r[w2])
                                   + pair_f(s_p[w1], s_r[w1], s_p[w3], s_r[w3])
                                   + pair_f(s_p[w2], s_r[w2], s_p[w3], s_r[w3]));
            // W = 1 + m_i + m_j + m_i*m_j  =>  weighted = S + 2R + TT
            atomicExch(&slotC[b], 2.0f * R + TT);                 // overwrite
            int s2 = 0;
            for (int g = 0; g < 5; ++g) {
                const int cg = s_hist[0][g] + s_hist[1][g] + s_hist[2][g] + s_hist[3][g];
                s2 += cg * cg;
            }
            atomicExch(&slotV[b], (float)(NN * NN - s2));         // overwrite
        }
    } else {
        // ---------------- tile path: one wave per 64x64 tile ----------------
        const int idx = blk - B;
        b = idx / TBLK;
        const int L = (idx % TBLK) * 4 + w;     // 0..135
        int rem = L, ti = 0;
        while (rem >= NT - ti) { rem -= NT - ti; ++ti; }
        const int tj = ti + rem;
        const size_t base = (size_t)b * NN;
        const int i0 = ti * 64, j0 = tj * 64;

        const float jp = pred[base + j0 + l];
        const float jr = rel [base + j0 + l];
        // per-wave private LDS segment (wave-lockstep + lgkmcnt, no barrier)
        s_seg[w][l] = make_float2(pred[base + i0 + l], rel[base + i0 + l]);

        float a = 0.0f;
        if (ti != tj) {
#pragma unroll 16
            for (int ii = 0; ii < 64; ++ii) {
                const float2 v = s_seg[w][ii];
                a += pair_f(v.x, v.y, jp, jr);
            }
        } else {
#pragma unroll 16
            for (int ii = 0; ii < 64; ++ii) {
                const float2 v = s_seg[w][ii];
                const float f = pair_f(v.x, v.y, jp, jr);
                a += (l > ii) ? f : 0.0f;       // strict upper triangle
            }
        }
        for (int off = 32; off > 0; off >>= 1) a += __shfl_down(a, off);
        if (l == 0)
            atomicExch(&slotT[(size_t)b * NTILES + L], 2.0f * a); // overwrite
    }

    // __syncthreads drains vmcnt: this block's slot writes are performed at
    // the coherence point before its ticket is taken.
    __syncthreads();
    if (t == 0) {
        unsigned int* ctr_b = (unsigned int*)(ws + OFF_CB + (size_t)b * 128);
        const unsigned int old = atomicInc(ctr_b, (unsigned int)(BPB - 1));
        s_flag = (old == (unsigned int)(BPB - 2)) ? 1 : 0;
    }
    __syncthreads();
    if (!s_flag) return;                         // block-uniform

    // ------------- batch winner: all 35 blocks of batch b are done -------------
    {
        float v = 0.0f;
        if (t < NTILES)            v = atomicAdd(&slotT[(size_t)b * NTILES + t], 0.0f);
        else if (t == NTILES)      s_corr = atomicAdd(&slotC[b], 0.0f);
        else if (t == NTILES + 1)  s_cnt  = atomicAdd(&slotV[b], 0.0f);
        for (int off = 32; off > 0; off >>= 1) v += __shfl_down(v, off);
        if (l == 0) s_red[w] = v;
        __syncthreads();
        if (t == 0) {
            const float S = s_red[0] + s_red[1] + s_red[2] + s_red[3];
            const float loss_b = (S + s_corr) / (s_cnt + 1e-8f);
            sinkf(atomicExch(&lossS[b], loss_b));        // ordered before ticket
            unsigned int* ctrG = (unsigned int*)(ws + OFF_CG);
            const unsigned int o2 = atomicInc(ctrG, (unsigned int)(B - 1));
            s_flag2 = (o2 == (unsigned int)(B - 2)) ? 1 : 0;
        }
        __syncthreads();
        if (s_flag2 && w == 0) {
            // ------------- global winner: all 32 batch losses written -------------
            float u = (l < B) ? atomicAdd(&lossS[l], 0.0f) : 0.0f;
            for (int off = 32; off > 0; off >>= 1) u += __shfl_down(u, off);
            if (l == 0) out[0] = u / (float)B;
        }
    }
}

extern "C" void kernel_launch(void* const* d_in, const int* in_sizes, int n_in,
                              void* d_out, int out_size, void* d_ws, size_t ws_size,
                              hipStream_t stream) {
    const float* pred = (const float*)d_in[0];
    const float* rel  = (const float*)d_in[1];
    float* out = (float*)d_out;

    const int B = in_sizes[0] / NN;  // 32

    fused_kernel<<<B + TBLK * B, BTH, 0, stream>>>(pred, rel, (char*)d_ws, out, B);
}

// Round 12
// 21.789 us; speedup vs baseline: 1.2873x; 1.1838x over previous
//
#include <hip/hip_runtime.h>
#include <math.h>

#define NN 1024
#define BTH 256
#define NT 16              // NN/64 tile-chunks per row
#define NTILES 136         // NT*(NT+1)/2 upper-triangle 64x64 tiles
#define TBLK 34            // tile blocks per batch (4 waves = 4 tiles each)
#define BPB (TBLK + 1)     // blocks per batch incl. its top-k block

// ws byte offsets. All data slots are OVERWRITTEN (atomicExch) every launch
// before any read -> no reset needed, immune to initial garbage/poison.
//   slotT[32][136] f32 @ 0       per-tile partial sums
//   slotC[32]      f32 @ 17408   per-batch top-k correction
//   slotV[32]      f32 @ 17536   per-batch valid-pair count
//   lossS[32]      f32 @ 17664   per-batch loss
//   ctrB[b]        u32 @ 17792 + b*128   (own cache line each)
//   ctrG           u32 @ 21888
// Tickets use atomicInc wraparound (LIMIT = P-1): counter cycles 0..P-1 and
// ANY start value >= P-1 (0xAA poison = 2.8e9, or the steady-state residue
// P-1 left by the previous launch) wraps to 0 at the first arrival, so the
// winner (old == P-2) is exactly the LAST arrival -- no reset dispatch needed.
#define OFF_T 0
#define OFF_C 17408
#define OFF_V 17536
#define OFF_L 17664
#define OFF_CB 17792
#define OFF_CG 21888

// f(i,j) = softplus(x) - t*x  (t = [ri>rj]), gated by valid = [ri!=rj].
// Identity: sp(x) - t*x = sp((1-2t)x)  =>  symmetric: f(i,j) = f(j,i).
__device__ __forceinline__ float pair_f(float pi, float ri, float pj, float rj) {
    const float x = pi - pj;
    const float y = (ri > rj) ? -x : x;
    const float e = __expf(-fabsf(y));
    const float f = fmaxf(y, 0.0f) + __logf(1.0f + e);
    return (ri != rj) ? f : 0.0f;
}

// Keep a returning atomic's result live -> compiler must waitcnt before the
// asm, ordering it ahead of any later vmem op in program order.
__device__ __forceinline__ void sinkf(float v) { asm volatile("" :: "v"(v)); }

// ---------------------------------------------------------------------------
// ONE dispatch, nothing else. Cross-block data via device-scope atomics only
// (coherent across XCDs, no fences). Per-batch counters on private 128-B
// lines (round-6 lesson: same-line contended atomics serialize ~60ns each).
// Ordering: overwrite-slot atomics -> __syncthreads (vmcnt(0) drain: slots
// performed at the coherence point) -> ticket atomicInc.
// ---------------------------------------------------------------------------
__global__ void __launch_bounds__(BTH)
fused_kernel(const float* __restrict__ pred, const float* __restrict__ rel,
             char* __restrict__ ws, float* __restrict__ out, int B) {
    const int t = threadIdx.x;
    const int w = t >> 6, l = t & 63;
    const int blk = blockIdx.x;

    __shared__ float  s_p[NN];
    __shared__ float  s_r[NN];
    __shared__ float2 s_seg[4][64];
    __shared__ float  s_rv[3][4];
    __shared__ int    s_ri[3][4];
    __shared__ int    s_hist[4][5];
    __shared__ float  s_red[4];
    __shared__ float  s_corr, s_cnt;
    __shared__ int    s_flag, s_flag2;

    float* slotT = (float*)(ws + OFF_T);
    float* slotC = (float*)(ws + OFF_C);
    float* slotV = (float*)(ws + OFF_V);
    float* lossS = (float*)(ws + OFF_L);

    int b;
    if (blk < B) {
        // ---------------- top-k path: one block per batch ----------------
        b = blk;
        const size_t base = (size_t)b * NN;
        const float4 p4 = ((const float4*)(pred + base))[t];
        const float4 r4 = ((const float4*)(rel  + base))[t];
        ((float4*)s_p)[t] = p4;
        ((float4*)s_r)[t] = r4;

        // grade histogram via ballots (no LDS atomics)
        for (int g = 0; g < 5; ++g) {
            const float gf = (float)g;
            int c = __popcll(__ballot(r4.x == gf)) + __popcll(__ballot(r4.y == gf))
                  + __popcll(__ballot(r4.z == gf)) + __popcll(__ballot(r4.w == gf));
            if (l == 0) s_hist[w][g] = c;
        }

        // top-3 from registers; tie-break: lower index wins (jax.lax.top_k)
        int w1 = -1, w2 = -1, w3 = -1;
        const int n0 = t * 4;
        for (int k = 0; k < 3; ++k) {
            float bv = -INFINITY;
            int   bi = NN;
            if (n0 + 0 != w1 && n0 + 0 != w2 && p4.x > bv) { bv = p4.x; bi = n0 + 0; }
            if (n0 + 1 != w1 && n0 + 1 != w2 && p4.y > bv) { bv = p4.y; bi = n0 + 1; }
            if (n0 + 2 != w1 && n0 + 2 != w2 && p4.z > bv) { bv = p4.z; bi = n0 + 2; }
            if (n0 + 3 != w1 && n0 + 3 != w2 && p4.w > bv) { bv = p4.w; bi = n0 + 3; }
            for (int off = 32; off > 0; off >>= 1) {
                const float ov = __shfl_xor(bv, off);
                const int   oi = __shfl_xor(bi, off);
                if (ov > bv || (ov == bv && oi < bi)) { bv = ov; bi = oi; }
            }
            if (l == 0) { s_rv[k][w] = bv; s_ri[k][w] = bi; }
            __syncthreads();
            bv = s_rv[k][0]; bi = s_ri[k][0];
            for (int q = 1; q < 4; ++q) {
                const float ov = s_rv[k][q]; const int oi = s_ri[k][q];
                if (ov > bv || (ov == bv && oi < bi)) { bv = ov; bi = oi; }
            }
            if (k == 0) w1 = bi; else if (k == 1) w2 = bi; else w3 = bi;
        }

        // unweighted rowsums over the 3 winners
        float part = 0.0f;
        for (int k = 0; k < 3; ++k) {
            const int row = (k == 0) ? w1 : (k == 1) ? w2 : w3;
            const float pk = s_p[row], rk = s_r[row];
#pragma unroll
            for (int c = 0; c < 4; ++c) {
                const int j = t + c * BTH;
                part += pair_f(pk, rk, s_p[j], s_r[j]);
            }
        }
        for (int off = 32; off > 0; off >>= 1) part += __shfl_down(part, off);
        if (l == 0) s_red[w] = part;
        __syncthreads();
        if (t == 0) {
            const float R = s_red[0] + s_red[1] + s_red[2] + s_red[3];
            const float TT = 2.0f * (pair_f(s_p[w1], s_r[w1], s_p[w2], s_r[w2])
                                   + pair_f(s_p[w1], s_r[w1], s_p[w3], s_r[w3])
                                   + pair_f(s_p[w2], s_r[w2], s_p[w3], s_r[w3]));
            // W = 1 + m_i + m_j + m_i*m_j  =>  weighted = S + 2R + TT
            atomicExch(&slotC[b], 2.0f * R + TT);                 // overwrite
            int s2 = 0;
            for (int g = 0; g < 5; ++g) {
                const int cg = s_hist[0][g] + s_hist[1][g] + s_hist[2][g] + s_hist[3][g];
                s2 += cg * cg;
            }
            atomicExch(&slotV[b], (float)(NN * NN - s2));         // overwrite
        }
    } else {
        // ---------------- tile path: one wave per 64x64 tile ----------------
        const int idx = blk - B;
        b = idx / TBLK;
        const int L = (idx % TBLK) * 4 + w;     // 0..135
        int rem = L, ti = 0;
        while (rem >= NT - ti) { rem -= NT - ti; ++ti; }
        const int tj = ti + rem;
        const size_t base = (size_t)b * NN;
        const int i0 = ti * 64, j0 = tj * 64;

        const float jp = pred[base + j0 + l];
        const float jr = rel [base + j0 + l];
        // per-wave private LDS segment (wave-lockstep + lgkmcnt, no barrier)
        s_seg[w][l] = make_float2(pred[base + i0 + l], rel[base + i0 + l]);

        float a = 0.0f;
        if (ti != tj) {
#pragma unroll 16
            for (int ii = 0; ii < 64; ++ii) {
                const float2 v = s_seg[w][ii];
                a += pair_f(v.x, v.y, jp, jr);
            }
        } else {
#pragma unroll 16
            for (int ii = 0; ii < 64; ++ii) {
                const float2 v = s_seg[w][ii];
                const float f = pair_f(v.x, v.y, jp, jr);
                a += (l > ii) ? f : 0.0f;       // strict upper triangle
            }
        }
        for (int off = 32; off > 0; off >>= 1) a += __shfl_down(a, off);
        if (l == 0)
            atomicExch(&slotT[(size_t)b * NTILES + L], 2.0f * a); // overwrite
    }

    // __syncthreads drains vmcnt: this block's slot writes are performed at
    // the coherence point before its ticket is taken.
    __syncthreads();
    if (t == 0) {
        unsigned int* ctr_b = (unsigned int*)(ws + OFF_CB + (size_t)b * 128);
        // cycle 0..BPB-1; any start >= BPB-1 wraps to 0 at first arrival,
        // so old == BPB-2 identifies the LAST (35th) arrival; leaves BPB-1.
        const unsigned int old = atomicInc(ctr_b, (unsigned int)(BPB - 1));
        s_flag = (old == (unsigned int)(BPB - 2)) ? 1 : 0;
    }
    __syncthreads();
    if (!s_flag) return;                         // block-uniform

    // ------------- batch winner: all 35 blocks of batch b are done -------------
    {
        float v = 0.0f;
        if (t < NTILES)            v = atomicAdd(&slotT[(size_t)b * NTILES + t], 0.0f);
        else if (t == NTILES)      s_corr = atomicAdd(&slotC[b], 0.0f);
        else if (t == NTILES + 1)  s_cnt  = atomicAdd(&slotV[b], 0.0f);
        for (int off = 32; off > 0; off >>= 1) v += __shfl_down(v, off);
        if (l == 0) s_red[w] = v;
        __syncthreads();
        if (t == 0) {
            const float S = s_red[0] + s_red[1] + s_red[2] + s_red[3];
            const float loss_b = (S + s_corr) / (s_cnt + 1e-8f);
            sinkf(atomicExch(&lossS[b], loss_b));        // ordered before ticket
            unsigned int* ctrG = (unsigned int*)(ws + OFF_CG);
            const unsigned int o2 = atomicInc(ctrG, (unsigned int)(B - 1));
            s_flag2 = (o2 == (unsigned int)(B - 2)) ? 1 : 0;
        }
        __syncthreads();
        if (s_flag2 && w == 0) {
            // ------------- global winner: all 32 batch losses written -------------
            float u = (l < B) ? atomicAdd(&lossS[l], 0.0f) : 0.0f;
            for (int off = 32; off > 0; off >>= 1) u += __shfl_down(u, off);
            if (l == 0) out[0] = u / (float)B;
        }
    }
}

extern "C" void kernel_launch(void* const* d_in, const int* in_sizes, int n_in,
                              void* d_out, int out_size, void* d_ws, size_t ws_size,
                              hipStream_t stream) {
    const float* pred = (const float*)d_in[0];
    const float* rel  = (const float*)d_in[1];
    float* out = (float*)d_out;

    const int B = in_sizes[0] / NN;  // 32

    fused_kernel<<<B + TBLK * B, BTH, 0, stream>>>(pred, rel, (char*)d_ws, out, B);
}